// Round 8
// baseline (182.469 us; speedup 1.0000x reference)
//
#include <hip/hip_runtime.h>
#include <hip/hip_bf16.h>
#include <math.h>

// DeformConv2D MI355X: b=4,c=64,H=W=128,KS=3,N=9 -> out[b,o,h,w] = sum_{c,n} W[o,c,n]*bilin(xpad,p)
// R16: revert R15's cooperative launch (harness graph-capture rejects it -> kernel never ran).
//      Two-kernel structure restored (R14 bodies verbatim). Kept R15's one safe idea: deform
//      processes 2 adjacent tiles per block (grid 2048->1024, rep loop; pairs share h0 row).
//      Loop-top __syncthreads() fences rep0 obuf2 reads vs rep1 P0 LDS writes.
//      Numerics bit-identical to R14 (absmax 0.03125).

typedef __attribute__((ext_vector_type(8)))  short short8;
typedef __attribute__((ext_vector_type(4)))  short short4_t;
typedef __attribute__((ext_vector_type(16))) float float16;
typedef __attribute__((ext_vector_type(2)))  float floatx2;
typedef __attribute__((ext_vector_type(4)))  unsigned uintx4;
typedef __attribute__((ext_vector_type(2)))  unsigned uintx2;

#define NPIX 65536
#define XS_STRIDE 580   // xs leading dim (bf16): dword stride 290 = 2 mod 32 -> 2-way (free)
#define K2_WS 68        // stage wp stride (64ch + 4 pad)
#define K2_RS 2312      // stage row stride (34*68)

// workspace layout (byte offsets)
#define XPB_B   0u           // bf16 hi padded NHWC x : 8,652,800 B
#define XPL_B   8652800u     // bf16 lo residual      : 8,652,800 B
#define WBB_B   17305600u    // W_conv bf16 MFMA B-frags: 73,728 B
#define WOH_B   17379328u    // W_off hi B-frags      : 36,864 B
#define WOL_B   17416192u    // W_off lo B-frags      : 36,864 B (end 17,453,056)

__device__ inline unsigned short f2bf(float f) {
    unsigned int u = __float_as_uint(f);
    u += 0x7fffu + ((u >> 16) & 1u);           // RNE
    return (unsigned short)(u >> 16);
}
__device__ inline float bfhi2f(unsigned int v) { return __uint_as_float(v & 0xffff0000u); }
__device__ inline float bflo2f(unsigned int v) { return __uint_as_float(v << 16); }
__device__ inline floatx2 up2(unsigned int v) {
    floatx2 r; r.x = bflo2f(v); r.y = bfhi2f(v); return r;
}

// ---------------------------------------------------------------- K1: pad/transpose + weight prep
__global__ __launch_bounds__(1024) void pad_prep(const float* __restrict__ x,
                                                 const float* __restrict__ W_off,
                                                 const float* __restrict__ W_conv,
                                                 char* __restrict__ wsb) {
    int t = threadIdx.x;
    if (blockIdx.x >= 520) {   // ---- weight prep: 16 blocks x 3456 items
        unsigned short* Wb  = (unsigned short*)(wsb + WBB_B);
        unsigned short* Woh = (unsigned short*)(wsb + WOH_B);
        unsigned short* Wol = (unsigned short*)(wsb + WOL_B);
        int wb = blockIdx.x - 520;
        for (int ii = t; ii < 3456; ii += 1024) {
            int e = wb * 3456 + ii;
            if (e < 36864) {
                int j = e & 7, lane = (e >> 3) & 63, t2 = e >> 9;
                int ks = t2 % 36, nt = t2 / 36;
                int k = ks * 16 + ((lane >> 5) << 3) + j;
                int n = nt * 32 + (lane & 31);
                Wb[e] = f2bf(W_conv[(n * 64 + (k & 63)) * 9 + (k >> 6)]);
            } else {
                int e2 = e - 36864;     // W_off hi/lo frags, N=32 (18 used)
                int j = e2 & 7, lane = (e2 >> 3) & 63, ksg = e2 >> 9;
                int k = ksg * 16 + ((lane >> 5) << 3) + j;
                int c = k & 63, tap = k >> 6, n = lane & 31;
                float v = 0.f;
                if (n < 18) { int ko = (n < 9) ? 2 * n : 2 * (n - 9) + 1; v = W_off[(ko * 64 + c) * 9 + tap]; }
                unsigned short hi = f2bf(v);
                Woh[e2] = hi;
                Wol[e2] = f2bf(v - bfhi2f((unsigned int)hi << 16));
            }
        }
        return;
    }
    uintx4* xpb4 = (uintx4*)(wsb + XPB_B);
    uintx4* xpl4 = (uintx4*)(wsb + XPL_B);
    const uintx4 zero4 = {0u, 0u, 0u, 0u};
    __shared__ float tile[64][129];
    int hp = blockIdx.x % 130, b = blockIdx.x / 130;
    int rowbase = ((b * 130 + hp) * 130) * 64;               // element (short) index
    if (hp == 0 || hp == 129) {                              // top/bottom pad rows
        int base4 = rowbase >> 3;                            // uint4 index
        for (int i = t; i < 1040; i += 1024) {
            xpb4[base4 + i] = zero4;
            xpl4[base4 + i] = zero4;
        }
        return;
    }
    int h = hp - 1;
    {   // ---- load: float4 over w, 2 iters (64c x 32 w-quads)
        const float4* x4 = (const float4*)x;
#pragma unroll
        for (int s = 0; s < 2; s++) {
            int idx = t + s * 1024;
            int c = idx >> 5, w4 = idx & 31;
            float4 v = x4[(((b * 64 + c) * 128) + h) * 32 + w4];
            tile[c][w4 * 4 + 0] = v.x;
            tile[c][w4 * 4 + 1] = v.y;
            tile[c][w4 * 4 + 2] = v.z;
            tile[c][w4 * 4 + 3] = v.w;
        }
    }
    __syncthreads();
    {   // ---- store: thread (w = t>>3, cq = t&7) -> channels 8cq..8cq+7, dwordx4 per plane
        int w = t >> 3, cq = t & 7;
        unsigned hd[4], ld[4];
#pragma unroll
        for (int j = 0; j < 4; j++) {
            float v0 = tile[cq * 8 + 2 * j][w];
            float v1 = tile[cq * 8 + 2 * j + 1][w];
            unsigned short h0 = f2bf(v0), h1 = f2bf(v1);
            unsigned short l0 = f2bf(v0 - bfhi2f((unsigned int)h0 << 16));
            unsigned short l1 = f2bf(v1 - bfhi2f((unsigned int)h1 << 16));
            hd[j] = (unsigned)h0 | ((unsigned)h1 << 16);
            ld[j] = (unsigned)l0 | ((unsigned)l1 << 16);
        }
        int a4 = ((rowbase + (w + 1) * 64) >> 3) + cq;       // uint4 index, 16B aligned
        uintx4 hv; hv.x = hd[0]; hv.y = hd[1]; hv.z = hd[2]; hv.w = hd[3];
        uintx4 lv; lv.x = ld[0]; lv.y = ld[1]; lv.z = ld[2]; lv.w = ld[3];
        xpb4[a4] = hv;
        xpl4[a4] = lv;
        // left/right pad columns (wp=0 and wp=129): 8 uint4 each per plane
        int base4 = rowbase >> 3;
        if (t < 8)          xpb4[base4 + t] = zero4;
        else if (t < 16)    xpl4[base4 + (t - 8)] = zero4;
        else if (t < 24)    xpb4[base4 + 129 * 8 + (t - 16)] = zero4;
        else if (t < 32)    xpl4[base4 + 129 * 8 + (t - 24)] = zero4;
    }
}

// ---------------------------------------------------------------- K2: fused, 8 waves, 2 tiles/block
// LDS 37,120 B total (4 blocks/CU = 32 waves = HW cap):
//   stage xh [0,13872) xl [13872,27744)  (P0-P1)
//   obuf [0,20480) float2-paired          (P2-P3a, after B2)
//   cdat: per-wave, wv*4640+3488, 36 x 32B in CONSUMPTION order (A:0-19 taps0-4, B:20-35)
//   xs   [0,37120)                        (P5a/P5b; overwrites cdat tail in verified-safe order)
//   obuf2 [0,33792)                       (P7, after B6)
__global__ __launch_bounds__(512, 8) void deform_fused(const float* __restrict__ b_off,
                                                       float* __restrict__ out,
                                                       char* __restrict__ wsb) {
    const uintx4* xpb4 = (const uintx4*)(wsb + XPB_B);
    const uintx4* xpl4 = (const uintx4*)(wsb + XPL_B);
    const short8* Woh = (const short8*)(wsb + WOH_B);
    const short8* Wol = (const short8*)(wsb + WOL_B);
    const short8* Wb  = (const short8*)(wsb + WBB_B);

    __shared__ __attribute__((aligned(16))) char smem[37120];
    unsigned short* xh = (unsigned short*)smem;              // stage hi
    unsigned short* xl = xh + 3 * K2_RS;                     // stage lo
    float* obuf = (float*)smem;                              // [8][32][20] float2-paired
    unsigned short* xs = (unsigned short*)smem;              // [32][580]
    float* obuf2 = (float*)smem;                             // [8][32][33]

    int t = threadIdx.x;
    int lane = t & 63, wv = t >> 6;                          // wv 0..7
    int m = lane & 31, half8 = (lane >> 5) << 3;

    for (int rep = 0; rep < 2; rep++) {
        int pixbase = ((int)blockIdx.x * 2 + rep) * 32;
        int w0 = pixbase & 127, h0 = (pixbase >> 7) & 127, bimg = pixbase >> 14;

        if (rep) __syncthreads();                            // fence rep0 obuf2 reads vs P0 writes

        // ---- P0: stage 3 rows x 34 cols x 64 ch hi/lo; uint4 loads, b64 LDS writes.
#pragma unroll
        for (int s = 0; s < 2; s++) {
            int i = t + s * 512;
            if (s == 0 || t < 304) {
                int row = i / 272, rem = i - row * 272;
                int wp = rem >> 3, q = rem & 7;
                int gq = ((bimg * 130 + h0 + row) * 130 + (w0 + wp)) * 8 + q;   // uint4 index
                uintx4 vh = xpb4[gq];
                uintx4 vl = xpl4[gq];
                int d = row * (K2_RS / 2) + wp * (K2_WS / 2) + q * 4;           // dword index
                uintx2 h01; h01.x = vh.x; h01.y = vh.y;
                uintx2 h23; h23.x = vh.z; h23.y = vh.w;
                uintx2 l01; l01.x = vl.x; l01.y = vl.y;
                uintx2 l23; l23.x = vl.z; l23.y = vl.w;
                *(uintx2*)((unsigned*)xh + d)     = h01;
                *(uintx2*)((unsigned*)xh + d + 2) = h23;
                *(uintx2*)((unsigned*)xl + d)     = l01;
                *(uintx2*)((unsigned*)xl + d + 2) = l23;
            }
        }
        __syncthreads();                                     // B1

        // ---- P1: offset conv via split-bf16 MFMA, all 8 waves (ksg split 5,5,5,5,4,4,4,4)
        float16 acc1;
#pragma unroll
        for (int r = 0; r < 16; r++) acc1[r] = 0.f;
        {
            int ks0  = (wv < 4) ? wv * 5 : 20 + (wv - 4) * 4;
            int kcnt = (wv < 4) ? 5 : 4;
            __builtin_amdgcn_s_setprio(1);
#pragma unroll
            for (int i = 0; i < 5; i++) {
                if (i < kcnt) {
                    int ksg = ks0 + i;
                    int tap = ksg >> 2;
                    int c0 = ((ksg & 3) << 4) + half8;
                    int ty = tap / 3, tx = tap - 3 * ty;
                    int eb = ty * K2_RS + (m + tx) * K2_WS + c0;
                    short4_t h0v = *(const short4_t*)(xh + eb);
                    short4_t h1v = *(const short4_t*)(xh + eb + 4);
                    short4_t l0v = *(const short4_t*)(xl + eb);
                    short4_t l1v = *(const short4_t*)(xl + eb + 4);
                    short8 ah = __builtin_shufflevector(h0v, h1v, 0, 1, 2, 3, 4, 5, 6, 7);
                    short8 al = __builtin_shufflevector(l0v, l1v, 0, 1, 2, 3, 4, 5, 6, 7);
                    short8 bh = Woh[ksg * 64 + lane];
                    short8 bl = Wol[ksg * 64 + lane];
                    acc1 = __builtin_amdgcn_mfma_f32_32x32x16_bf16(ah, bh, acc1, 0, 0, 0);
                    acc1 = __builtin_amdgcn_mfma_f32_32x32x16_bf16(ah, bl, acc1, 0, 0, 0);
                    acc1 = __builtin_amdgcn_mfma_f32_32x32x16_bf16(al, bh, acc1, 0, 0, 0);
                }
            }
            __builtin_amdgcn_s_setprio(0);
        }
        __syncthreads();                                     // B2
        // ---- P2: partials -> obuf[wv][row][pair] (col 2n=orow_n, 2n+1=ocol_n)
        if (m < 18) {
            int cpair = (m < 9) ? 2 * m : 2 * (m - 9) + 1;
#pragma unroll
            for (int r = 0; r < 16; r++) {
                int row = (r & 3) + 8 * (r >> 2) + 4 * (lane >> 5);
                obuf[(wv * 32 + row) * 20 + cpair] = acc1[r];
            }
        }
        __syncthreads();                                     // B3

        // ---- P3a: per-(pixel,tap) bilinear setup (exact fp32 decisions) -> registers
        bool act = (t < 288);
        unsigned rofs0 = 0, rofs1 = 0, rofs2 = 0, rofs3 = 0;
        float rg0 = 0.f, rg1 = 0.f, rg2 = 0.f, rg3 = 0.f;
        if (act) {
            int it = t;
            int p = (it * 7282) >> 16;              // /9
            int n = it - p * 9;
            float orow = b_off[2 * n], ocol = b_off[2 * n + 1];
#pragma unroll
            for (int kq = 0; kq < 8; kq++) {
                floatx2 pr2v = *(const floatx2*)&obuf[(kq * 32 + p) * 20 + 2 * n];
                orow += pr2v.x;
                ocol += pr2v.y;
            }
            float pr = (float)(h0 + (n / 3)) + orow;
            float pc = (float)(w0 + p + (n % 3)) + ocol;
            float flr = floorf(pr), flc = floorf(pc);
            float qlt_r = fminf(fmaxf(flr, 0.f), 129.f);
            float qlt_c = fminf(fmaxf(flc, 0.f), 129.f);
            float qrb_r = fminf(fmaxf(flr + 1.f, 0.f), 129.f);
            float qrb_c = fminf(fmaxf(flc + 1.f, 0.f), 129.f);
            bool mr = (pr < 1.f) || (pr > 128.f);
            bool mc = (pc < 1.f) || (pc > 128.f);
            float pr2 = mr ? flr : pr; pr2 = fminf(fmaxf(pr2, 0.f), 129.f);
            float pc2 = mc ? flc : pc; pc2 = fminf(fmaxf(pc2, 0.f), 129.f);
            float wr_lt = 1.f + (qlt_r - pr2);
            float wr_rb = 1.f - (qrb_r - pr2);
            float wc_lt = 1.f + (qlt_c - pc2);
            float wc_rb = 1.f - (qrb_c - pc2);
            int ilt_r = (int)qlt_r, ilt_c = (int)qlt_c;
            int irb_r = (int)qrb_r, irb_c = (int)qrb_c;
            rg0 = wr_lt * wc_lt; rg1 = wr_rb * wc_rb;        // Gx, Gy
            rg2 = wr_lt * wc_rb; rg3 = wr_rb * wc_lt;        // Gz, Gw
            rofs0 = (unsigned)(ilt_r * 16640 + ilt_c * 128); // LT
            rofs1 = (unsigned)(irb_r * 16640 + irb_c * 128); // RB
            rofs2 = (unsigned)(ilt_r * 16640 + irb_c * 128); // LB
            rofs3 = (unsigned)(irb_r * 16640 + ilt_c * 128); // RT
        }
        __syncthreads();                                     // B3b
        // ---- P3b: write cdat records in CONSUMPTION order: A k=p*5+n (n<5), B k=20+p*4+(n-5)
        if (act) {
            int it = t;
            int pall = (it * 7282) >> 16;           // /9
            int n = it - pall * 9;
            int ww = pall >> 2, p = pall & 3;
            int kt = (n < 5) ? (p * 5 + n) : (20 + p * 4 + (n - 5));
            char* rec = smem + ww * 4640 + 3488 + 32 * kt;
            *(uint4*)rec = make_uint4(rofs0, rofs1, rofs2, rofs3);
            *(float4*)(rec + 16) = make_float4(rg0, rg1, rg2, rg3);
        }
        __syncthreads();                                     // B4: cdat visible

        // ---- shared gather context
        int g = lane >> 3;
        unsigned s16 = (unsigned)((((lane & 7) + g) & 7) * 16);
        const char* bp = (const char*)(wsb + XPB_B) + (size_t)bimg * (130 * 130 * 128);
        const char* crec = smem + wv * 4640 + 3488 + 32 * g;
        unsigned wvb = (unsigned)(wv * 4640);
        char* xsb = (char*)smem;

        // ---- P5a: gather taps 0-4 (20 records, 2.5 iters)
#pragma unroll
        for (int i = 0; i < 3; i++) {
            if (i < 2 || g < 4) {
                int k = 8 * i + g;
                uintx4 offs = *(const uintx4*)(crec + 256 * i);
                float4 wt   = *(const float4*)(crec + 256 * i + 16);
                unsigned p = ((unsigned)k * 13108u) >> 16;   // /5
                unsigned n = (unsigned)k - 5u * p;
                unsigned wa = wvb + p * 1160u + (n << 7) + s16;
                uintx4 v0 = *(const uintx4*)(bp + (offs.x + s16));
                uintx4 v1 = *(const uintx4*)(bp + (offs.y + s16));
                uintx4 v2 = *(const uintx4*)(bp + (offs.z + s16));
                uintx4 v3 = *(const uintx4*)(bp + (offs.w + s16));
                floatx2 wx; wx.x = wt.x; wx.y = wt.x;
                floatx2 wy; wy.x = wt.y; wy.y = wt.y;
                floatx2 wz; wz.x = wt.z; wz.y = wt.z;
                floatx2 wwv; wwv.x = wt.w; wwv.y = wt.w;
                unsigned r0, r1, r2, r3;
                { floatx2 f = __builtin_elementwise_fma(wx, up2(v0.x), __builtin_elementwise_fma(wy, up2(v1.x), __builtin_elementwise_fma(wz, up2(v2.x), wwv * up2(v3.x))));
                  __hip_bfloat162 pk2 = __float22bfloat162_rn(make_float2(f.x, f.y)); r0 = *(unsigned*)&pk2; }
                { floatx2 f = __builtin_elementwise_fma(wx, up2(v0.y), __builtin_elementwise_fma(wy, up2(v1.y), __builtin_elementwise_fma(wz, up2(v2.y), wwv * up2(v3.y))));
                  __hip_bfloat162 pk2 = __float22bfloat162_rn(make_float2(f.x, f.y)); r1 = *(unsigned*)&pk2; }
                { floatx2 f = __builtin_elementwise_fma(wx, up2(v0.z), __builtin_elementwise_fma(wy, up2(v1.z), __builtin_elementwise_fma(wz, up2(v2.z), wwv * up2(v3.z))));
                  __hip_bfloat162 pk2 = __float22bfloat162_rn(make_float2(f.x, f.y)); r2 = *(unsigned*)&pk2; }
                { floatx2 f = __builtin_elementwise_fma(wx, up2(v0.w), __builtin_elementwise_fma(wy, up2(v1.w), __builtin_elementwise_fma(wz, up2(v2.w), wwv * up2(v3.w))));
                  __hip_bfloat162 pk2 = __float22bfloat162_rn(make_float2(f.x, f.y)); r3 = *(unsigned*)&pk2; }
                uintx2 w01; w01.x = r0; w01.y = r1;
                uintx2 w23; w23.x = r2; w23.y = r3;
                *(uintx2*)(xsb + wa)     = w01;
                *(uintx2*)(xsb + wa + 8) = w23;
            }
        }
        __syncthreads();                                     // B5a: taps 0-4 visible

        int nt = wv & 1, kh = wv >> 1;
        float16 acc;
#pragma unroll
        for (int r = 0; r < 16; r++) acc[r] = 0.f;

        // ---- issue P5b iter0 loads (records 20+g), overlap with P6a MFMA
        uintx4 bv0, bv1, bv2, bv3; float4 wtB0; unsigned waB0;
        {
            int k = g;
            uintx4 offs = *(const uintx4*)(crec + 640);
            wtB0 = *(const float4*)(crec + 640 + 16);
            unsigned p = (unsigned)k >> 2;
            unsigned n5 = (unsigned)k & 3;
            waB0 = wvb + p * 1160u + ((5u + n5) << 7) + s16;
            bv0 = *(const uintx4*)(bp + (offs.x + s16));
            bv1 = *(const uintx4*)(bp + (offs.y + s16));
            bv2 = *(const uintx4*)(bp + (offs.z + s16));
            bv3 = *(const uintx4*)(bp + (offs.w + s16));
        }

        // ---- P6a: contraction MFMA on taps 0-4 (ksg = kh*5 + 0..4)
        __builtin_amdgcn_s_setprio(1);
#pragma unroll
        for (int i2 = 0; i2 < 5; i2++) {
            int ksg = kh * 5 + i2;
            int baseE = m * XS_STRIDE + ksg * 16 + half8;
            short4_t a0 = *(const short4_t*)(xs + baseE);
            short4_t a1 = *(const short4_t*)(xs + baseE + 4);
            short8 af = __builtin_shufflevector(a0, a1, 0, 1, 2, 3, 4, 5, 6, 7);
            short8 bfv = Wb[(nt * 36 + ksg) * 64 + lane];
            acc = __builtin_amdgcn_mfma_f32_32x32x16_bf16(af, bfv, acc, 0, 0, 0);
        }
        __builtin_amdgcn_s_setprio(0);

        // ---- P5b iter0 combine + write; then iter1 (records 28+g)
        {
            floatx2 wx; wx.x = wtB0.x; wx.y = wtB0.x;
            floatx2 wy; wy.x = wtB0.y; wy.y = wtB0.y;
            floatx2 wz; wz.x = wtB0.z; wz.y = wtB0.z;
            floatx2 wwv; wwv.x = wtB0.w; wwv.y = wtB0.w;
            unsigned r0, r1, r2, r3;
            { floatx2 f = __builtin_elementwise_fma(wx, up2(bv0.x), __builtin_elementwise_fma(wy, up2(bv1.x), __builtin_elementwise_fma(wz, up2(bv2.x), wwv * up2(bv3.x))));
              __hip_bfloat162 pk2 = __float22bfloat162_rn(make_float2(f.x, f.y)); r0 = *(unsigned*)&pk2; }
            { floatx2 f = __builtin_elementwise_fma(wx, up2(bv0.y), __builtin_elementwise_fma(wy, up2(bv1.y), __builtin_elementwise_fma(wz, up2(bv2.y), wwv * up2(bv3.y))));
              __hip_bfloat162 pk2 = __float22bfloat162_rn(make_float2(f.x, f.y)); r1 = *(unsigned*)&pk2; }
            { floatx2 f = __builtin_elementwise_fma(wx, up2(bv0.z), __builtin_elementwise_fma(wy, up2(bv1.z), __builtin_elementwise_fma(wz, up2(bv2.z), wwv * up2(bv3.z))));
              __hip_bfloat162 pk2 = __float22bfloat162_rn(make_float2(f.x, f.y)); r2 = *(unsigned*)&pk2; }
            { floatx2 f = __builtin_elementwise_fma(wx, up2(bv0.w), __builtin_elementwise_fma(wy, up2(bv1.w), __builtin_elementwise_fma(wz, up2(bv2.w), wwv * up2(bv3.w))));
              __hip_bfloat162 pk2 = __float22bfloat162_rn(make_float2(f.x, f.y)); r3 = *(unsigned*)&pk2; }
            uintx2 w01; w01.x = r0; w01.y = r1;
            uintx2 w23; w23.x = r2; w23.y = r3;
            *(uintx2*)(xsb + waB0)     = w01;
            *(uintx2*)(xsb + waB0 + 8) = w23;
        }
        {
            int k = 8 + g;
            uintx4 offs = *(const uintx4*)(crec + 896);
            float4 wt   = *(const float4*)(crec + 896 + 16);
            unsigned p = (unsigned)k >> 2;
            unsigned n5 = (unsigned)k & 3;
            unsigned wa = wvb + p * 1160u + ((5u + n5) << 7) + s16;
            uintx4 v0 = *(const uintx4*)(bp + (offs.x + s16));
            uintx4 v1 = *(const uintx4*)(bp + (offs.y + s16));
            uintx4 v2 = *(const uintx4*)(bp + (offs.z + s16));
            uintx4 v3 = *(const uintx4*)(bp + (offs.w + s16));
            floatx2 wx; wx.x = wt.x; wx.y = wt.x;
            floatx2 wy; wy.x = wt.y; wy.y = wt.y;
            floatx2 wz; wz.x = wt.z; wz.y = wt.z;
            floatx2 wwv; wwv.x = wt.w; wwv.y = wt.w;
            unsigned r0, r1, r2, r3;
            { floatx2 f = __builtin_elementwise_fma(wx, up2(v0.x), __builtin_elementwise_fma(wy, up2(v1.x), __builtin_elementwise_fma(wz, up2(v2.x), wwv * up2(v3.x))));
              __hip_bfloat162 pk2 = __float22bfloat162_rn(make_float2(f.x, f.y)); r0 = *(unsigned*)&pk2; }
            { floatx2 f = __builtin_elementwise_fma(wx, up2(v0.y), __builtin_elementwise_fma(wy, up2(v1.y), __builtin_elementwise_fma(wz, up2(v2.y), wwv * up2(v3.y))));
              __hip_bfloat162 pk2 = __float22bfloat162_rn(make_float2(f.x, f.y)); r1 = *(unsigned*)&pk2; }
            { floatx2 f = __builtin_elementwise_fma(wx, up2(v0.z), __builtin_elementwise_fma(wy, up2(v1.z), __builtin_elementwise_fma(wz, up2(v2.z), wwv * up2(v3.z))));
              __hip_bfloat162 pk2 = __float22bfloat162_rn(make_float2(f.x, f.y)); r2 = *(unsigned*)&pk2; }
            { floatx2 f = __builtin_elementwise_fma(wx, up2(v0.w), __builtin_elementwise_fma(wy, up2(v1.w), __builtin_elementwise_fma(wz, up2(v2.w), wwv * up2(v3.w))));
              __hip_bfloat162 pk2 = __float22bfloat162_rn(make_float2(f.x, f.y)); r3 = *(unsigned*)&pk2; }
            uintx2 w01; w01.x = r0; w01.y = r1;
            uintx2 w23; w23.x = r2; w23.y = r3;
            *(uintx2*)(xsb + wa)     = w01;
            *(uintx2*)(xsb + wa + 8) = w23;
        }
        __syncthreads();                                     // B5b: taps 5-8 visible

        // ---- P6b: contraction MFMA on taps 5-8 (ksg = 20 + kh*4 + 0..3)
        __builtin_amdgcn_s_setprio(1);
#pragma unroll
        for (int i2 = 0; i2 < 4; i2++) {
            int ksg = 20 + kh * 4 + i2;
            int baseE = m * XS_STRIDE + ksg * 16 + half8;
            short4_t a0 = *(const short4_t*)(xs + baseE);
            short4_t a1 = *(const short4_t*)(xs + baseE + 4);
            short8 af = __builtin_shufflevector(a0, a1, 0, 1, 2, 3, 4, 5, 6, 7);
            short8 bfv = Wb[(nt * 36 + ksg) * 64 + lane];
            acc = __builtin_amdgcn_mfma_f32_32x32x16_bf16(af, bfv, acc, 0, 0, 0);
        }
        __builtin_amdgcn_s_setprio(0);
        __syncthreads();                                     // B6: xs reads done -> obuf2 alias safe
        // ---- P7: each (kh,nt) wave writes its own obuf2 region; single barrier; add at store
#pragma unroll
        for (int r = 0; r < 16; r++) {
            int mrow = (r & 3) + 8 * (r >> 2) + 4 * (lane >> 5);
            obuf2[(kh * 2 + nt) * 1056 + mrow * 33 + m] = acc[r];
        }
        __syncthreads();                                     // B7
#pragma unroll
        for (int i = 0; i < 4; i++) {
            int lin = i * 512 + t;
            int o = lin >> 5, p = lin & 31;
            int oi = (o >> 5) * 1056 + p * 33 + (o & 31);
            float v = (obuf2[oi] + obuf2[oi + 2112])
                    + (obuf2[oi + 4224] + obuf2[oi + 6336]); // kh0..kh3 partials
            out[((bimg * 64 + o) << 14) + (h0 << 7) + w0 + p] = v;
        }
    }
}

// ---------------------------------------------------------------- launch
extern "C" void kernel_launch(void* const* d_in, const int* in_sizes, int n_in,
                              void* d_out, int out_size, void* d_ws, size_t ws_size,
                              hipStream_t stream) {
    const float* x      = (const float*)d_in[0];
    const float* W_off  = (const float*)d_in[1];
    const float* b_off  = (const float*)d_in[2];
    const float* W_conv = (const float*)d_in[3];
    char* wsb  = (char*)d_ws;            // needs 17,453,056 B
    float* out = (float*)d_out;

    hipLaunchKernelGGL(pad_prep, dim3(536), dim3(1024), 0, stream, x, W_off, W_conv, wsb);
    hipLaunchKernelGGL(deform_fused, dim3(NPIX / 64), dim3(512), 0, stream, b_off, out, wsb);
}

// Round 9
// 111.099 us; speedup vs baseline: 1.6424x; 1.6424x over previous
//
#include <hip/hip_runtime.h>
#include <hip/hip_bf16.h>
#include <math.h>

// DeformConv2D MI355X: b=4,c=64,H=W=128,KS=3,N=9 -> out[b,o,h,w] = sum_{c,n} W[o,c,n]*bilin(xpad,p)
// R17: REVERT to R12 (best measured: 110.91 us). R16's 2-tile rep loop spilled to scratch
//      (FETCH 18.5->245 MB, WRITE 16->226 MB symmetric = scratch traffic; deform 40->115 us):
//      doubled live ranges + launch_bounds(512,8) VGPR cap 64 -> allocator spills.
//      This file is byte-for-byte the R12 source (verified absmax 0.03125).

typedef __attribute__((ext_vector_type(8)))  short short8;
typedef __attribute__((ext_vector_type(4)))  short short4_t;
typedef __attribute__((ext_vector_type(16))) float float16;
typedef __attribute__((ext_vector_type(2)))  float floatx2;
typedef __attribute__((ext_vector_type(4)))  unsigned uintx4;
typedef __attribute__((ext_vector_type(2)))  unsigned uintx2;

#define NPIX 65536
#define XS_STRIDE 580   // xs leading dim (bf16): dword stride 290 = 2 mod 32 -> 2-way (free)
#define K2_WS 68        // stage wp stride (64ch + 4 pad)
#define K2_RS 2312      // stage row stride (34*68)

// workspace layout (byte offsets)
#define XPB_B   0u           // bf16 hi padded NHWC x : 8,652,800 B
#define XPL_B   8652800u     // bf16 lo residual      : 8,652,800 B
#define WBB_B   17305600u    // W_conv bf16 MFMA B-frags: 73,728 B
#define WOH_B   17379328u    // W_off hi B-frags      : 36,864 B
#define WOL_B   17416192u    // W_off lo B-frags      : 36,864 B (end 17,453,056)

__device__ inline unsigned short f2bf(float f) {
    unsigned int u = __float_as_uint(f);
    u += 0x7fffu + ((u >> 16) & 1u);           // RNE
    return (unsigned short)(u >> 16);
}
__device__ inline float bfhi2f(unsigned int v) { return __uint_as_float(v & 0xffff0000u); }
__device__ inline float bflo2f(unsigned int v) { return __uint_as_float(v << 16); }
__device__ inline floatx2 up2(unsigned int v) {
    floatx2 r; r.x = bflo2f(v); r.y = bfhi2f(v); return r;
}

// ---------------------------------------------------------------- K1: pad/transpose + weight prep
__global__ __launch_bounds__(1024) void pad_prep(const float* __restrict__ x,
                                                 const float* __restrict__ W_off,
                                                 const float* __restrict__ W_conv,
                                                 char* __restrict__ wsb) {
    unsigned short* xpb = (unsigned short*)(wsb + XPB_B);
    unsigned short* xpl = (unsigned short*)(wsb + XPL_B);
    int t = threadIdx.x;
    if (blockIdx.x >= 520) {   // ---- weight prep: 16 blocks x 3456 items
        unsigned short* Wb  = (unsigned short*)(wsb + WBB_B);
        unsigned short* Woh = (unsigned short*)(wsb + WOH_B);
        unsigned short* Wol = (unsigned short*)(wsb + WOL_B);
        int wb = blockIdx.x - 520;
        for (int ii = t; ii < 3456; ii += 1024) {
            int e = wb * 3456 + ii;
            if (e < 36864) {
                int j = e & 7, lane = (e >> 3) & 63, t2 = e >> 9;
                int ks = t2 % 36, nt = t2 / 36;
                int k = ks * 16 + ((lane >> 5) << 3) + j;
                int n = nt * 32 + (lane & 31);
                Wb[e] = f2bf(W_conv[(n * 64 + (k & 63)) * 9 + (k >> 6)]);
            } else {
                int e2 = e - 36864;     // W_off hi/lo frags, N=32 (18 used)
                int j = e2 & 7, lane = (e2 >> 3) & 63, ksg = e2 >> 9;
                int k = ksg * 16 + ((lane >> 5) << 3) + j;
                int c = k & 63, tap = k >> 6, n = lane & 31;
                float v = 0.f;
                if (n < 18) { int ko = (n < 9) ? 2 * n : 2 * (n - 9) + 1; v = W_off[(ko * 64 + c) * 9 + tap]; }
                unsigned short hi = f2bf(v);
                Woh[e2] = hi;
                Wol[e2] = f2bf(v - bfhi2f((unsigned int)hi << 16));
            }
        }
        return;
    }
    __shared__ float tile[64][129];
    int hp = blockIdx.x % 130, b = blockIdx.x / 130;
    int rowbase = ((b * 130 + hp) * 130) * 64;
    if (hp == 0 || hp == 129) {
        for (int i = t; i < 130 * 32; i += 1024) {
            ((unsigned*)(xpb + rowbase))[i] = 0u;
            ((unsigned*)(xpl + rowbase))[i] = 0u;
        }
        return;
    }
    int h = hp - 1;
    {
        int w = t & 127, cq = t >> 7;
#pragma unroll
        for (int cc = 0; cc < 8; cc++) {
            int c = cq + cc * 8;
            tile[c][w] = x[(((b * 64 + c) * 128) + h) * 128 + w];   // coalesced over w
        }
    }
    __syncthreads();
    {
        int c2 = (t & 31) * 2, wq = t >> 5;
        if (wq == 0) { ((unsigned*)(xpb + rowbase))[t & 31] = 0u; ((unsigned*)(xpl + rowbase))[t & 31] = 0u; }
        if (wq == 1) { ((unsigned*)(xpb + rowbase + 129 * 64))[t & 31] = 0u; ((unsigned*)(xpl + rowbase + 129 * 64))[t & 31] = 0u; }
#pragma unroll
        for (int w = wq; w < 128; w += 32) {
            float v0 = tile[c2][w], v1 = tile[c2 + 1][w];
            unsigned short h0 = f2bf(v0), h1 = f2bf(v1);
            unsigned short l0 = f2bf(v0 - bfhi2f((unsigned int)h0 << 16));
            unsigned short l1 = f2bf(v1 - bfhi2f((unsigned int)h1 << 16));
            int ad = (rowbase + (w + 1) * 64) / 2 + (t & 31);
            ((unsigned*)xpb)[ad] = (unsigned)h0 | ((unsigned)h1 << 16);
            ((unsigned*)xpl)[ad] = (unsigned)l0 | ((unsigned)l1 << 16);
        }
    }
}

// ---------------------------------------------------------------- K2: fused, 8 waves / 32 px
// LDS 37,120 B total (4 blocks/CU):
//   stage xh [0,13872) xl [13872,27744)  (P0-P1)
//   obuf [0,19456)                        (P2-P3a, after B2)
//   cdat: per-wave, wv*4640+3488, 36 x 32B {uint4 offs; float4 wt}  (P3b-P5, after B3b)
//   xs   [0,37120)                        (P5-P6; overwrites cdat tail in verified-safe order)
//   obuf2 [0,33792)                       (P7, after B6)
__global__ __launch_bounds__(512, 8) void deform_fused(const float* __restrict__ b_off,
                                                       float* __restrict__ out,
                                                       char* __restrict__ wsb) {
    const uintx4* xpb4 = (const uintx4*)(wsb + XPB_B);
    const uintx4* xpl4 = (const uintx4*)(wsb + XPL_B);
    const short8* Woh = (const short8*)(wsb + WOH_B);
    const short8* Wol = (const short8*)(wsb + WOL_B);
    const short8* Wb  = (const short8*)(wsb + WBB_B);

    __shared__ __attribute__((aligned(16))) char smem[37120];
    unsigned short* xh = (unsigned short*)smem;              // stage hi
    unsigned short* xl = xh + 3 * K2_RS;                     // stage lo
    float* obuf = (float*)smem;                              // [8][32][19]
    unsigned short* xs = (unsigned short*)smem;              // [32][580]
    float* obuf2 = (float*)smem;                             // [8][32][33]

    int t = threadIdx.x;
    int lane = t & 63, wv = t >> 6;                          // wv 0..7
    int pixbase = blockIdx.x * 32;
    int w0 = pixbase & 127, h0 = (pixbase >> 7) & 127, bimg = pixbase >> 14;
    int m = lane & 31, half8 = (lane >> 5) << 3;

    // ---- P0: stage 3 rows x 34 cols x 64 ch hi/lo; uint4 loads, b64 LDS writes.
    // 816 quad-items = 3 rows x 34 wp x 8 quads.
#pragma unroll
    for (int s = 0; s < 2; s++) {
        int i = t + s * 512;
        if (s == 0 || t < 304) {
            int row = i / 272, rem = i - row * 272;
            int wp = rem >> 3, q = rem & 7;
            int gq = ((bimg * 130 + h0 + row) * 130 + (w0 + wp)) * 8 + q;   // uint4 index
            uintx4 vh = xpb4[gq];
            uintx4 vl = xpl4[gq];
            int d = row * (K2_RS / 2) + wp * (K2_WS / 2) + q * 4;           // dword index (even)
            uintx2 h01; h01.x = vh.x; h01.y = vh.y;
            uintx2 h23; h23.x = vh.z; h23.y = vh.w;
            uintx2 l01; l01.x = vl.x; l01.y = vl.y;
            uintx2 l23; l23.x = vl.z; l23.y = vl.w;
            *(uintx2*)((unsigned*)xh + d)     = h01;
            *(uintx2*)((unsigned*)xh + d + 2) = h23;
            *(uintx2*)((unsigned*)xl + d)     = l01;
            *(uintx2*)((unsigned*)xl + d + 2) = l23;
        }
    }
    __syncthreads();                                         // B1

    // ---- P1: offset conv via split-bf16 MFMA, all 8 waves (ksg split 5,5,5,5,4,4,4,4)
    float16 acc1;
#pragma unroll
    for (int r = 0; r < 16; r++) acc1[r] = 0.f;
    {
        int ks0  = (wv < 4) ? wv * 5 : 20 + (wv - 4) * 4;
        int kcnt = (wv < 4) ? 5 : 4;
#pragma unroll
        for (int i = 0; i < 5; i++) {
            if (i < kcnt) {
                int ksg = ks0 + i;
                int tap = ksg >> 2;
                int c0 = ((ksg & 3) << 4) + half8;
                int ty = tap / 3, tx = tap - 3 * ty;
                int eb = ty * K2_RS + (m + tx) * K2_WS + c0;
                short4_t h0v = *(const short4_t*)(xh + eb);
                short4_t h1v = *(const short4_t*)(xh + eb + 4);
                short4_t l0v = *(const short4_t*)(xl + eb);
                short4_t l1v = *(const short4_t*)(xl + eb + 4);
                short8 ah = __builtin_shufflevector(h0v, h1v, 0, 1, 2, 3, 4, 5, 6, 7);
                short8 al = __builtin_shufflevector(l0v, l1v, 0, 1, 2, 3, 4, 5, 6, 7);
                short8 bh = Woh[ksg * 64 + lane];
                short8 bl = Wol[ksg * 64 + lane];
                acc1 = __builtin_amdgcn_mfma_f32_32x32x16_bf16(ah, bh, acc1, 0, 0, 0);
                acc1 = __builtin_amdgcn_mfma_f32_32x32x16_bf16(ah, bl, acc1, 0, 0, 0);
                acc1 = __builtin_amdgcn_mfma_f32_32x32x16_bf16(al, bh, acc1, 0, 0, 0);
            }
        }
    }
    __syncthreads();                                         // B2: stage reads done, obuf fresh
    // ---- P2: partials -> obuf[wv][row][n] (all 8 waves, n<18 used, stride 19)
    if (m < 18) {
#pragma unroll
        for (int r = 0; r < 16; r++) {
            int row = (r & 3) + 8 * (r >> 2) + 4 * (lane >> 5);
            obuf[(wv * 32 + row) * 19 + m] = acc1[r];
        }
    }
    __syncthreads();                                         // B3

    // ---- P3a: per-(pixel,tap) bilinear setup (exact fp32 decisions) -> registers
    bool act = (t < 288);
    unsigned rofs0 = 0, rofs1 = 0, rofs2 = 0, rofs3 = 0;
    float rg0 = 0.f, rg1 = 0.f, rg2 = 0.f, rg3 = 0.f;
    if (act) {
        int it = t;
        int p = (it * 7282) >> 16;              // /9
        int n = it - p * 9;
        float orow = b_off[2 * n], ocol = b_off[2 * n + 1];
#pragma unroll
        for (int kq = 0; kq < 8; kq++) {
            orow += obuf[(kq * 32 + p) * 19 + n];
            ocol += obuf[(kq * 32 + p) * 19 + 9 + n];
        }
        float pr = (float)(h0 + (n / 3)) + orow;
        float pc = (float)(w0 + p + (n % 3)) + ocol;
        float flr = floorf(pr), flc = floorf(pc);
        float qlt_r = fminf(fmaxf(flr, 0.f), 129.f);
        float qlt_c = fminf(fmaxf(flc, 0.f), 129.f);
        float qrb_r = fminf(fmaxf(flr + 1.f, 0.f), 129.f);
        float qrb_c = fminf(fmaxf(flc + 1.f, 0.f), 129.f);
        bool mr = (pr < 1.f) || (pr > 128.f);
        bool mc = (pc < 1.f) || (pc > 128.f);
        float pr2 = mr ? flr : pr; pr2 = fminf(fmaxf(pr2, 0.f), 129.f);
        float pc2 = mc ? flc : pc; pc2 = fminf(fmaxf(pc2, 0.f), 129.f);
        float wr_lt = 1.f + (qlt_r - pr2);
        float wr_rb = 1.f - (qrb_r - pr2);
        float wc_lt = 1.f + (qlt_c - pc2);
        float wc_rb = 1.f - (qrb_c - pc2);
        int ilt_r = (int)qlt_r, ilt_c = (int)qlt_c;
        int irb_r = (int)qrb_r, irb_c = (int)qrb_c;
        rg0 = wr_lt * wc_lt; rg1 = wr_rb * wc_rb;            // Gx, Gy
        rg2 = wr_lt * wc_rb; rg3 = wr_rb * wc_lt;            // Gz, Gw
        rofs0 = (unsigned)(ilt_r * 16640 + ilt_c * 128);     // LT
        rofs1 = (unsigned)(irb_r * 16640 + irb_c * 128);     // RB
        rofs2 = (unsigned)(ilt_r * 16640 + irb_c * 128);     // LB
        rofs3 = (unsigned)(irb_r * 16640 + ilt_c * 128);     // RT
    }
    __syncthreads();                                         // B3b: obuf reads done -> cdat may overwrite
    // ---- P3b: write cdat records into owning wave's xs-tail region
    if (act) {
        int it = t;
        int ww = (it * 7282) >> 18;             // /36
        int jj = it - ww * 36;
        char* rec = smem + ww * 4640 + 3488 + 32 * jj;
        *(uint4*)rec = make_uint4(rofs0, rofs1, rofs2, rofs3);
        *(float4*)(rec + 16) = make_float4(rg0, rg1, rg2, rg3);
    }
    __syncthreads();                                         // B4: cdat visible

    // ---- P5: gather, 8-lane groups, 8 items/wave-iter (4 full iters + 1 half).
    // Lane (g,sub_raw) handles dwords 4*rot..4*rot+3 of item j=8i+g, rot=(sub_raw+g)&7
    // (rotation makes b64 write banks provably distinct). dwordx4 loads; packed f32 fma.
    {
        int g = lane >> 3;
        unsigned s16 = (unsigned)((((lane & 7) + g) & 7) * 16);
        const char* bp = (const char*)(wsb + XPB_B) + (size_t)bimg * (130 * 130 * 128);
        const char* crec = smem + wv * 4640 + 3488 + 32 * g;
        unsigned wvb = (unsigned)(wv * 4640);
        char* xsb = (char*)smem;
#pragma unroll
        for (int i = 0; i < 5; i++) {
            if (i < 4 || g < 4) {
                uintx4 offs = *(const uintx4*)(crec + 256 * i);
                float4 wt   = *(const float4*)(crec + 256 * i + 16);
                uintx4 v0 = *(const uintx4*)(bp + (offs.x + s16));
                uintx4 v1 = *(const uintx4*)(bp + (offs.y + s16));
                uintx4 v2 = *(const uintx4*)(bp + (offs.z + s16));
                uintx4 v3 = *(const uintx4*)(bp + (offs.w + s16));
                floatx2 wx; wx.x = wt.x; wx.y = wt.x;
                floatx2 wy; wy.x = wt.y; wy.y = wt.y;
                floatx2 wz; wz.x = wt.z; wz.y = wt.z;
                floatx2 wwv; wwv.x = wt.w; wwv.y = wt.w;
                int jj = 8 * i + g;
                unsigned q9 = (unsigned)((jj * 7282) >> 16);
                unsigned wa = wvb + ((unsigned)jj << 7) + (q9 << 3) + s16;
                unsigned r0, r1, r2, r3;
                {
                    floatx2 f = __builtin_elementwise_fma(wx, up2(v0.x),
                                 __builtin_elementwise_fma(wy, up2(v1.x),
                                  __builtin_elementwise_fma(wz, up2(v2.x), wwv * up2(v3.x))));
                    __hip_bfloat162 pk2 = __float22bfloat162_rn(make_float2(f.x, f.y));
                    r0 = *(unsigned*)&pk2;
                }
                {
                    floatx2 f = __builtin_elementwise_fma(wx, up2(v0.y),
                                 __builtin_elementwise_fma(wy, up2(v1.y),
                                  __builtin_elementwise_fma(wz, up2(v2.y), wwv * up2(v3.y))));
                    __hip_bfloat162 pk2 = __float22bfloat162_rn(make_float2(f.x, f.y));
                    r1 = *(unsigned*)&pk2;
                }
                {
                    floatx2 f = __builtin_elementwise_fma(wx, up2(v0.z),
                                 __builtin_elementwise_fma(wy, up2(v1.z),
                                  __builtin_elementwise_fma(wz, up2(v2.z), wwv * up2(v3.z))));
                    __hip_bfloat162 pk2 = __float22bfloat162_rn(make_float2(f.x, f.y));
                    r2 = *(unsigned*)&pk2;
                }
                {
                    floatx2 f = __builtin_elementwise_fma(wx, up2(v0.w),
                                 __builtin_elementwise_fma(wy, up2(v1.w),
                                  __builtin_elementwise_fma(wz, up2(v2.w), wwv * up2(v3.w))));
                    __hip_bfloat162 pk2 = __float22bfloat162_rn(make_float2(f.x, f.y));
                    r3 = *(unsigned*)&pk2;
                }
                uintx2 w01; w01.x = r0; w01.y = r1;
                uintx2 w23; w23.x = r2; w23.y = r3;
                *(uintx2*)(xsb + wa)     = w01;
                *(uintx2*)(xsb + wa + 8) = w23;
            }
        }
    }
    __syncthreads();                                         // B5

    // ---- P6: contraction MFMA. wave: nt = N-tile (32 outs), kh = K-quarter (144)
    int nt = wv & 1, kh = wv >> 1;
    float16 acc;
#pragma unroll
    for (int r = 0; r < 16; r++) acc[r] = 0.f;
#pragma unroll
    for (int i2 = 0; i2 < 9; i2++) {
        int ksg = kh * 9 + i2;
        int baseE = m * XS_STRIDE + ksg * 16 + half8;
        short4_t a0 = *(const short4_t*)(xs + baseE);        // b64: stride 290dw -> 2-way only
        short4_t a1 = *(const short4_t*)(xs + baseE + 4);
        short8 af = __builtin_shufflevector(a0, a1, 0, 1, 2, 3, 4, 5, 6, 7);
        short8 bfv = Wb[(nt * 36 + ksg) * 64 + lane];        // coalesced 1KB, L2-resident
        acc = __builtin_amdgcn_mfma_f32_32x32x16_bf16(af, bfv, acc, 0, 0, 0);
    }
    __syncthreads();                                         // B6: all xs reads done -> obuf2 alias safe
    // ---- P7: each (kh,nt) wave writes its own obuf2 region; single barrier; add at store
#pragma unroll
    for (int r = 0; r < 16; r++) {
        int mrow = (r & 3) + 8 * (r >> 2) + 4 * (lane >> 5);
        obuf2[(kh * 2 + nt) * 1056 + mrow * 33 + m] = acc[r];
    }
    __syncthreads();                                         // B7
#pragma unroll
    for (int i = 0; i < 4; i++) {
        int lin = i * 512 + t;
        int o = lin >> 5, p = lin & 31;
        int oi = (o >> 5) * 1056 + p * 33 + (o & 31);
        float v = (obuf2[oi] + obuf2[oi + 2112])
                + (obuf2[oi + 4224] + obuf2[oi + 6336]);     // kh0..kh3 partials
        out[((bimg * 64 + o) << 14) + (h0 << 7) + w0 + p] = v;
    }
}

// ---------------------------------------------------------------- launch
extern "C" void kernel_launch(void* const* d_in, const int* in_sizes, int n_in,
                              void* d_out, int out_size, void* d_ws, size_t ws_size,
                              hipStream_t stream) {
    const float* x      = (const float*)d_in[0];
    const float* W_off  = (const float*)d_in[1];
    const float* b_off  = (const float*)d_in[2];
    const float* W_conv = (const float*)d_in[3];
    char* wsb  = (char*)d_ws;            // needs 17,453,056 B
    float* out = (float*)d_out;

    hipLaunchKernelGGL(pad_prep, dim3(536), dim3(1024), 0, stream, x, W_off, W_conv, wsb);
    hipLaunchKernelGGL(deform_fused, dim3(NPIX / 32), dim3(512), 0, stream, b_off, out, wsb);
}

// Round 10
// 110.091 us; speedup vs baseline: 1.6574x; 1.0092x over previous
//
#include <hip/hip_runtime.h>
#include <hip/hip_bf16.h>
#include <math.h>

// DeformConv2D MI355X: b=4,c=64,H=W=128,KS=3,N=9 -> out[b,o,h,w] = sum_{c,n} W[o,c,n]*bilin(xpad,p)
// R18: R17 (=R12, 110.9us best) + software-pipelined P5 gather (T14): prefetch next item's
//      cdat record + 4 corner loads before combining current item -> 2 items in flight/wave
//      (VGPR 40 -> ~60, under the 64 cap; spill tripwire = FETCH/WRITE counters).
//      Record reads move EARLIER only -> verified cdat-overwrite order preserved.
//      Combine fma pairing/nesting unchanged -> bit-identical (absmax 0.03125).

typedef __attribute__((ext_vector_type(8)))  short short8;
typedef __attribute__((ext_vector_type(4)))  short short4_t;
typedef __attribute__((ext_vector_type(16))) float float16;
typedef __attribute__((ext_vector_type(2)))  float floatx2;
typedef __attribute__((ext_vector_type(4)))  unsigned uintx4;
typedef __attribute__((ext_vector_type(2)))  unsigned uintx2;

#define NPIX 65536
#define XS_STRIDE 580   // xs leading dim (bf16): dword stride 290 = 2 mod 32 -> 2-way (free)
#define K2_WS 68        // stage wp stride (64ch + 4 pad)
#define K2_RS 2312      // stage row stride (34*68)

// workspace layout (byte offsets)
#define XPB_B   0u           // bf16 hi padded NHWC x : 8,652,800 B
#define XPL_B   8652800u     // bf16 lo residual      : 8,652,800 B
#define WBB_B   17305600u    // W_conv bf16 MFMA B-frags: 73,728 B
#define WOH_B   17379328u    // W_off hi B-frags      : 36,864 B
#define WOL_B   17416192u    // W_off lo B-frags      : 36,864 B (end 17,453,056)

__device__ inline unsigned short f2bf(float f) {
    unsigned int u = __float_as_uint(f);
    u += 0x7fffu + ((u >> 16) & 1u);           // RNE
    return (unsigned short)(u >> 16);
}
__device__ inline float bfhi2f(unsigned int v) { return __uint_as_float(v & 0xffff0000u); }
__device__ inline float bflo2f(unsigned int v) { return __uint_as_float(v << 16); }
__device__ inline floatx2 up2(unsigned int v) {
    floatx2 r; r.x = bflo2f(v); r.y = bfhi2f(v); return r;
}

// ---------------------------------------------------------------- K1: pad/transpose + weight prep
__global__ __launch_bounds__(1024) void pad_prep(const float* __restrict__ x,
                                                 const float* __restrict__ W_off,
                                                 const float* __restrict__ W_conv,
                                                 char* __restrict__ wsb) {
    unsigned short* xpb = (unsigned short*)(wsb + XPB_B);
    unsigned short* xpl = (unsigned short*)(wsb + XPL_B);
    int t = threadIdx.x;
    if (blockIdx.x >= 520) {   // ---- weight prep: 16 blocks x 3456 items
        unsigned short* Wb  = (unsigned short*)(wsb + WBB_B);
        unsigned short* Woh = (unsigned short*)(wsb + WOH_B);
        unsigned short* Wol = (unsigned short*)(wsb + WOL_B);
        int wb = blockIdx.x - 520;
        for (int ii = t; ii < 3456; ii += 1024) {
            int e = wb * 3456 + ii;
            if (e < 36864) {
                int j = e & 7, lane = (e >> 3) & 63, t2 = e >> 9;
                int ks = t2 % 36, nt = t2 / 36;
                int k = ks * 16 + ((lane >> 5) << 3) + j;
                int n = nt * 32 + (lane & 31);
                Wb[e] = f2bf(W_conv[(n * 64 + (k & 63)) * 9 + (k >> 6)]);
            } else {
                int e2 = e - 36864;     // W_off hi/lo frags, N=32 (18 used)
                int j = e2 & 7, lane = (e2 >> 3) & 63, ksg = e2 >> 9;
                int k = ksg * 16 + ((lane >> 5) << 3) + j;
                int c = k & 63, tap = k >> 6, n = lane & 31;
                float v = 0.f;
                if (n < 18) { int ko = (n < 9) ? 2 * n : 2 * (n - 9) + 1; v = W_off[(ko * 64 + c) * 9 + tap]; }
                unsigned short hi = f2bf(v);
                Woh[e2] = hi;
                Wol[e2] = f2bf(v - bfhi2f((unsigned int)hi << 16));
            }
        }
        return;
    }
    __shared__ float tile[64][129];
    int hp = blockIdx.x % 130, b = blockIdx.x / 130;
    int rowbase = ((b * 130 + hp) * 130) * 64;
    if (hp == 0 || hp == 129) {
        for (int i = t; i < 130 * 32; i += 1024) {
            ((unsigned*)(xpb + rowbase))[i] = 0u;
            ((unsigned*)(xpl + rowbase))[i] = 0u;
        }
        return;
    }
    int h = hp - 1;
    {
        int w = t & 127, cq = t >> 7;
#pragma unroll
        for (int cc = 0; cc < 8; cc++) {
            int c = cq + cc * 8;
            tile[c][w] = x[(((b * 64 + c) * 128) + h) * 128 + w];   // coalesced over w
        }
    }
    __syncthreads();
    {
        int c2 = (t & 31) * 2, wq = t >> 5;
        if (wq == 0) { ((unsigned*)(xpb + rowbase))[t & 31] = 0u; ((unsigned*)(xpl + rowbase))[t & 31] = 0u; }
        if (wq == 1) { ((unsigned*)(xpb + rowbase + 129 * 64))[t & 31] = 0u; ((unsigned*)(xpl + rowbase + 129 * 64))[t & 31] = 0u; }
#pragma unroll
        for (int w = wq; w < 128; w += 32) {
            float v0 = tile[c2][w], v1 = tile[c2 + 1][w];
            unsigned short h0 = f2bf(v0), h1 = f2bf(v1);
            unsigned short l0 = f2bf(v0 - bfhi2f((unsigned int)h0 << 16));
            unsigned short l1 = f2bf(v1 - bfhi2f((unsigned int)h1 << 16));
            int ad = (rowbase + (w + 1) * 64) / 2 + (t & 31);
            ((unsigned*)xpb)[ad] = (unsigned)h0 | ((unsigned)h1 << 16);
            ((unsigned*)xpl)[ad] = (unsigned)l0 | ((unsigned)l1 << 16);
        }
    }
}

// ---------------------------------------------------------------- K2: fused, 8 waves / 32 px
// LDS 37,120 B total (4 blocks/CU):
//   stage xh [0,13872) xl [13872,27744)  (P0-P1)
//   obuf [0,19456)                        (P2-P3a, after B2)
//   cdat: per-wave, wv*4640+3488, 36 x 32B {uint4 offs; float4 wt}  (P3b-P5, after B3b)
//   xs   [0,37120)                        (P5-P6; overwrites cdat tail in verified-safe order)
//   obuf2 [0,33792)                       (P7, after B6)
__global__ __launch_bounds__(512, 8) void deform_fused(const float* __restrict__ b_off,
                                                       float* __restrict__ out,
                                                       char* __restrict__ wsb) {
    const uintx4* xpb4 = (const uintx4*)(wsb + XPB_B);
    const uintx4* xpl4 = (const uintx4*)(wsb + XPL_B);
    const short8* Woh = (const short8*)(wsb + WOH_B);
    const short8* Wol = (const short8*)(wsb + WOL_B);
    const short8* Wb  = (const short8*)(wsb + WBB_B);

    __shared__ __attribute__((aligned(16))) char smem[37120];
    unsigned short* xh = (unsigned short*)smem;              // stage hi
    unsigned short* xl = xh + 3 * K2_RS;                     // stage lo
    float* obuf = (float*)smem;                              // [8][32][19]
    unsigned short* xs = (unsigned short*)smem;              // [32][580]
    float* obuf2 = (float*)smem;                             // [8][32][33]

    int t = threadIdx.x;
    int lane = t & 63, wv = t >> 6;                          // wv 0..7
    int pixbase = blockIdx.x * 32;
    int w0 = pixbase & 127, h0 = (pixbase >> 7) & 127, bimg = pixbase >> 14;
    int m = lane & 31, half8 = (lane >> 5) << 3;

    // ---- P0: stage 3 rows x 34 cols x 64 ch hi/lo; uint4 loads, b64 LDS writes.
#pragma unroll
    for (int s = 0; s < 2; s++) {
        int i = t + s * 512;
        if (s == 0 || t < 304) {
            int row = i / 272, rem = i - row * 272;
            int wp = rem >> 3, q = rem & 7;
            int gq = ((bimg * 130 + h0 + row) * 130 + (w0 + wp)) * 8 + q;   // uint4 index
            uintx4 vh = xpb4[gq];
            uintx4 vl = xpl4[gq];
            int d = row * (K2_RS / 2) + wp * (K2_WS / 2) + q * 4;           // dword index (even)
            uintx2 h01; h01.x = vh.x; h01.y = vh.y;
            uintx2 h23; h23.x = vh.z; h23.y = vh.w;
            uintx2 l01; l01.x = vl.x; l01.y = vl.y;
            uintx2 l23; l23.x = vl.z; l23.y = vl.w;
            *(uintx2*)((unsigned*)xh + d)     = h01;
            *(uintx2*)((unsigned*)xh + d + 2) = h23;
            *(uintx2*)((unsigned*)xl + d)     = l01;
            *(uintx2*)((unsigned*)xl + d + 2) = l23;
        }
    }
    __syncthreads();                                         // B1

    // ---- P1: offset conv via split-bf16 MFMA, all 8 waves (ksg split 5,5,5,5,4,4,4,4)
    float16 acc1;
#pragma unroll
    for (int r = 0; r < 16; r++) acc1[r] = 0.f;
    {
        int ks0  = (wv < 4) ? wv * 5 : 20 + (wv - 4) * 4;
        int kcnt = (wv < 4) ? 5 : 4;
#pragma unroll
        for (int i = 0; i < 5; i++) {
            if (i < kcnt) {
                int ksg = ks0 + i;
                int tap = ksg >> 2;
                int c0 = ((ksg & 3) << 4) + half8;
                int ty = tap / 3, tx = tap - 3 * ty;
                int eb = ty * K2_RS + (m + tx) * K2_WS + c0;
                short4_t h0v = *(const short4_t*)(xh + eb);
                short4_t h1v = *(const short4_t*)(xh + eb + 4);
                short4_t l0v = *(const short4_t*)(xl + eb);
                short4_t l1v = *(const short4_t*)(xl + eb + 4);
                short8 ah = __builtin_shufflevector(h0v, h1v, 0, 1, 2, 3, 4, 5, 6, 7);
                short8 al = __builtin_shufflevector(l0v, l1v, 0, 1, 2, 3, 4, 5, 6, 7);
                short8 bh = Woh[ksg * 64 + lane];
                short8 bl = Wol[ksg * 64 + lane];
                acc1 = __builtin_amdgcn_mfma_f32_32x32x16_bf16(ah, bh, acc1, 0, 0, 0);
                acc1 = __builtin_amdgcn_mfma_f32_32x32x16_bf16(ah, bl, acc1, 0, 0, 0);
                acc1 = __builtin_amdgcn_mfma_f32_32x32x16_bf16(al, bh, acc1, 0, 0, 0);
            }
        }
    }
    __syncthreads();                                         // B2: stage reads done, obuf fresh
    // ---- P2: partials -> obuf[wv][row][n] (all 8 waves, n<18 used, stride 19)
    if (m < 18) {
#pragma unroll
        for (int r = 0; r < 16; r++) {
            int row = (r & 3) + 8 * (r >> 2) + 4 * (lane >> 5);
            obuf[(wv * 32 + row) * 19 + m] = acc1[r];
        }
    }
    __syncthreads();                                         // B3

    // ---- P3a: per-(pixel,tap) bilinear setup (exact fp32 decisions) -> registers
    bool act = (t < 288);
    unsigned rofs0 = 0, rofs1 = 0, rofs2 = 0, rofs3 = 0;
    float rg0 = 0.f, rg1 = 0.f, rg2 = 0.f, rg3 = 0.f;
    if (act) {
        int it = t;
        int p = (it * 7282) >> 16;              // /9
        int n = it - p * 9;
        float orow = b_off[2 * n], ocol = b_off[2 * n + 1];
#pragma unroll
        for (int kq = 0; kq < 8; kq++) {
            orow += obuf[(kq * 32 + p) * 19 + n];
            ocol += obuf[(kq * 32 + p) * 19 + 9 + n];
        }
        float pr = (float)(h0 + (n / 3)) + orow;
        float pc = (float)(w0 + p + (n % 3)) + ocol;
        float flr = floorf(pr), flc = floorf(pc);
        float qlt_r = fminf(fmaxf(flr, 0.f), 129.f);
        float qlt_c = fminf(fmaxf(flc, 0.f), 129.f);
        float qrb_r = fminf(fmaxf(flr + 1.f, 0.f), 129.f);
        float qrb_c = fminf(fmaxf(flc + 1.f, 0.f), 129.f);
        bool mr = (pr < 1.f) || (pr > 128.f);
        bool mc = (pc < 1.f) || (pc > 128.f);
        float pr2 = mr ? flr : pr; pr2 = fminf(fmaxf(pr2, 0.f), 129.f);
        float pc2 = mc ? flc : pc; pc2 = fminf(fmaxf(pc2, 0.f), 129.f);
        float wr_lt = 1.f + (qlt_r - pr2);
        float wr_rb = 1.f - (qrb_r - pr2);
        float wc_lt = 1.f + (qlt_c - pc2);
        float wc_rb = 1.f - (qrb_c - pc2);
        int ilt_r = (int)qlt_r, ilt_c = (int)qlt_c;
        int irb_r = (int)qrb_r, irb_c = (int)qrb_c;
        rg0 = wr_lt * wc_lt; rg1 = wr_rb * wc_rb;            // Gx, Gy
        rg2 = wr_lt * wc_rb; rg3 = wr_rb * wc_lt;            // Gz, Gw
        rofs0 = (unsigned)(ilt_r * 16640 + ilt_c * 128);     // LT
        rofs1 = (unsigned)(irb_r * 16640 + irb_c * 128);     // RB
        rofs2 = (unsigned)(ilt_r * 16640 + irb_c * 128);     // LB
        rofs3 = (unsigned)(irb_r * 16640 + ilt_c * 128);     // RT
    }
    __syncthreads();                                         // B3b: obuf reads done -> cdat may overwrite
    // ---- P3b: write cdat records into owning wave's xs-tail region
    if (act) {
        int it = t;
        int ww = (it * 7282) >> 18;             // /36
        int jj = it - ww * 36;
        char* rec = smem + ww * 4640 + 3488 + 32 * jj;
        *(uint4*)rec = make_uint4(rofs0, rofs1, rofs2, rofs3);
        *(float4*)(rec + 16) = make_float4(rg0, rg1, rg2, rg3);
    }
    __syncthreads();                                         // B4: cdat visible

    // ---- P5: gather, 8-lane groups, 8 items/wave-iter, SOFTWARE-PIPELINED by 1 item:
    // iter i issues item 8(i+1)+g's record read + 4 corner loads BEFORE combining item 8i+g.
    // Record reads only move EARLIER vs R12 -> cdat-overwrite safety order preserved.
    {
        int g = lane >> 3;
        unsigned s16 = (unsigned)((((lane & 7) + g) & 7) * 16);
        const char* bp = (const char*)(wsb + XPB_B) + (size_t)bimg * (130 * 130 * 128);
        const char* crec = smem + wv * 4640 + 3488 + 32 * g;
        unsigned wvb = (unsigned)(wv * 4640);
        char* xsb = (char*)smem;
        // prologue: item g (iter 0) — exists for all groups
        uintx4 offs = *(const uintx4*)(crec);
        float4 wt   = *(const float4*)(crec + 16);
        uintx4 v0 = *(const uintx4*)(bp + (offs.x + s16));
        uintx4 v1 = *(const uintx4*)(bp + (offs.y + s16));
        uintx4 v2 = *(const uintx4*)(bp + (offs.z + s16));
        uintx4 v3 = *(const uintx4*)(bp + (offs.w + s16));
#pragma unroll
        for (int i = 0; i < 5; i++) {
            uintx4 n0, n1, n2, n3; float4 wtn;
            if (i < 4) {                                     // prefetch item 8(i+1)+g
                if (i < 3 || g < 4) {                        // existence guard for iter 4
                    uintx4 offsN = *(const uintx4*)(crec + 256 * (i + 1));
                    wtn = *(const float4*)(crec + 256 * (i + 1) + 16);
                    n0 = *(const uintx4*)(bp + (offsN.x + s16));
                    n1 = *(const uintx4*)(bp + (offsN.y + s16));
                    n2 = *(const uintx4*)(bp + (offsN.z + s16));
                    n3 = *(const uintx4*)(bp + (offsN.w + s16));
                }
            }
            if (i < 4 || g < 4) {                            // combine + write item 8i+g
                floatx2 wx; wx.x = wt.x; wx.y = wt.x;
                floatx2 wy; wy.x = wt.y; wy.y = wt.y;
                floatx2 wz; wz.x = wt.z; wz.y = wt.z;
                floatx2 wwv; wwv.x = wt.w; wwv.y = wt.w;
                int jj = 8 * i + g;
                unsigned q9 = (unsigned)((jj * 7282) >> 16);
                unsigned wa = wvb + ((unsigned)jj << 7) + (q9 << 3) + s16;
                unsigned r0, r1, r2, r3;
                {
                    floatx2 f = __builtin_elementwise_fma(wx, up2(v0.x),
                                 __builtin_elementwise_fma(wy, up2(v1.x),
                                  __builtin_elementwise_fma(wz, up2(v2.x), wwv * up2(v3.x))));
                    __hip_bfloat162 pk2 = __float22bfloat162_rn(make_float2(f.x, f.y));
                    r0 = *(unsigned*)&pk2;
                }
                {
                    floatx2 f = __builtin_elementwise_fma(wx, up2(v0.y),
                                 __builtin_elementwise_fma(wy, up2(v1.y),
                                  __builtin_elementwise_fma(wz, up2(v2.y), wwv * up2(v3.y))));
                    __hip_bfloat162 pk2 = __float22bfloat162_rn(make_float2(f.x, f.y));
                    r1 = *(unsigned*)&pk2;
                }
                {
                    floatx2 f = __builtin_elementwise_fma(wx, up2(v0.z),
                                 __builtin_elementwise_fma(wy, up2(v1.z),
                                  __builtin_elementwise_fma(wz, up2(v2.z), wwv * up2(v3.z))));
                    __hip_bfloat162 pk2 = __float22bfloat162_rn(make_float2(f.x, f.y));
                    r2 = *(unsigned*)&pk2;
                }
                {
                    floatx2 f = __builtin_elementwise_fma(wx, up2(v0.w),
                                 __builtin_elementwise_fma(wy, up2(v1.w),
                                  __builtin_elementwise_fma(wz, up2(v2.w), wwv * up2(v3.w))));
                    __hip_bfloat162 pk2 = __float22bfloat162_rn(make_float2(f.x, f.y));
                    r3 = *(unsigned*)&pk2;
                }
                uintx2 w01; w01.x = r0; w01.y = r1;
                uintx2 w23; w23.x = r2; w23.y = r3;
                *(uintx2*)(xsb + wa)     = w01;
                *(uintx2*)(xsb + wa + 8) = w23;
            }
            v0 = n0; v1 = n1; v2 = n2; v3 = n3; wt = wtn;    // rotate pipeline
        }
    }
    __syncthreads();                                         // B5

    // ---- P6: contraction MFMA. wave: nt = N-tile (32 outs), kh = K-quarter (144)
    int nt = wv & 1, kh = wv >> 1;
    float16 acc;
#pragma unroll
    for (int r = 0; r < 16; r++) acc[r] = 0.f;
#pragma unroll
    for (int i2 = 0; i2 < 9; i2++) {
        int ksg = kh * 9 + i2;
        int baseE = m * XS_STRIDE + ksg * 16 + half8;
        short4_t a0 = *(const short4_t*)(xs + baseE);        // b64: stride 290dw -> 2-way only
        short4_t a1 = *(const short4_t*)(xs + baseE + 4);
        short8 af = __builtin_shufflevector(a0, a1, 0, 1, 2, 3, 4, 5, 6, 7);
        short8 bfv = Wb[(nt * 36 + ksg) * 64 + lane];        // coalesced 1KB, L2-resident
        acc = __builtin_amdgcn_mfma_f32_32x32x16_bf16(af, bfv, acc, 0, 0, 0);
    }
    __syncthreads();                                         // B6: all xs reads done -> obuf2 alias safe
    // ---- P7: each (kh,nt) wave writes its own obuf2 region; single barrier; add at store
#pragma unroll
    for (int r = 0; r < 16; r++) {
        int mrow = (r & 3) + 8 * (r >> 2) + 4 * (lane >> 5);
        obuf2[(kh * 2 + nt) * 1056 + mrow * 33 + m] = acc[r];
    }
    __syncthreads();                                         // B7
#pragma unroll
    for (int i = 0; i < 4; i++) {
        int lin = i * 512 + t;
        int o = lin >> 5, p = lin & 31;
        int oi = (o >> 5) * 1056 + p * 33 + (o & 31);
        float v = (obuf2[oi] + obuf2[oi + 2112])
                + (obuf2[oi + 4224] + obuf2[oi + 6336]);     // kh0..kh3 partials
        out[((bimg * 64 + o) << 14) + (h0 << 7) + w0 + p] = v;
    }
}

// ---------------------------------------------------------------- launch
extern "C" void kernel_launch(void* const* d_in, const int* in_sizes, int n_in,
                              void* d_out, int out_size, void* d_ws, size_t ws_size,
                              hipStream_t stream) {
    const float* x      = (const float*)d_in[0];
    const float* W_off  = (const float*)d_in[1];
    const float* b_off  = (const float*)d_in[2];
    const float* W_conv = (const float*)d_in[3];
    char* wsb  = (char*)d_ws;            // needs 17,453,056 B
    float* out = (float*)d_out;

    hipLaunchKernelGGL(pad_prep, dim3(536), dim3(1024), 0, stream, x, W_off, W_conv, wsb);
    hipLaunchKernelGGL(deform_fused, dim3(NPIX / 32), dim3(512), 0, stream, b_off, out, wsb);
}